// Round 4
// baseline (307.669 us; speedup 1.0000x reference)
//
#include <hip/hip_runtime.h>

#define VQ_EPS 1e-12f

// Kernel 1: normalize codebook rows. Outputs:
//   cbn   [512][64] row-major  (epilogue gather of the winning row)
//   cbT   [64][512] chan-major (main loop: contiguous wave-uniform floats per
//                               (c, ktile) -> s_load_dwordx16 path)
//   knorm2[512]                (sum(cbn^2) AFTER normalization, like reference)
__global__ __launch_bounds__(64) void cb_norm_kernel(const float* __restrict__ cb,
                                                     float* __restrict__ cbn,
                                                     float* __restrict__ cbT,
                                                     float* __restrict__ knorm2) {
    const int k = blockIdx.x;       // 512 rows
    const int c = threadIdx.x;      // 64 channels
    float v = cb[k * 64 + c];
    float s = v * v;
    #pragma unroll
    for (int off = 32; off > 0; off >>= 1) s += __shfl_xor(s, off, 64);
    float n = sqrtf(s);
    float cn = v / fmaxf(n, VQ_EPS);     // elementwise divide, like F.normalize
    cbn[k * 64 + c] = cn;
    cbT[c * 512 + k] = cn;
    float s2 = cn * cn;
    #pragma unroll
    for (int off = 32; off > 0; off >>= 1) s2 += __shfl_xor(s2, off, 64);
    if (c == 0) knorm2[k] = s2;
}

// Kernel 2: one thread per pixel; lane = w -> coalesced x loads/stores.
// K tiled by 32 scalar accumulators (small enough that the allocator keeps
// them live instead of loop-interchanging -- R2/R3 showed it refuses >=64-reg
// arrays). x is streamed from global INSIDE the c-loop by design: 1024
// coalesced re-loads/thread = ~2 MB/CU of L1 traffic (~14 us), hidden under
// the ~57 us fp32 FMA floor. Codebook on the scalar pipe via cbT (uniform
// address -> s_load_dwordx16), knorm2 likewise.
__global__ __launch_bounds__(256) void vq_kernel(const float* __restrict__ x,
                                                 const float* __restrict__ cbn,
                                                 const float* __restrict__ cbT,
                                                 const float* __restrict__ knorm2,
                                                 float* __restrict__ codes,
                                                 float* __restrict__ idxout) {
    const int p = blockIdx.x * 256 + threadIdx.x;   // 131072 pixels
    const int w = p & 63;
    const int h = (p >> 6) & 63;
    const int b = p >> 12;

    const float* xp = x + ((size_t)b * 64 * 4096) + h * 64 + w;

    // ||x_raw||: one streaming pass (also warms L1/L2).
    float ss = 0.0f;
    #pragma unroll 8
    for (int c = 0; c < 64; ++c) {
        float a = xp[(size_t)c * 4096];
        ss = fmaf(a, a, ss);
    }
    const float inv = 1.0f / fmaxf(sqrtf(ss), VQ_EPS);  // IEEE divide (no fast-math)
    const float m2  = -2.0f * inv;   // score_k = knorm2[k] + m2 * (x_raw . cbn_k)

    float best = 3.0e38f;
    int bestk = 0;

    for (int t = 0; t < 16; ++t) {
        const int kbase = t * 32;

        float acc[32];
        #pragma unroll
        for (int i = 0; i < 32; ++i) acc[i] = 0.0f;

        #pragma unroll 4
        for (int c = 0; c < 64; ++c) {
            const float xc = xp[(size_t)c * 4096];               // coalesced, L1-hot
            const float* cbc = cbT + (size_t)c * 512 + kbase;    // uniform -> s_load
            #pragma unroll
            for (int i = 0; i < 32; ++i)
                acc[i] = fmaf(xc, cbc[i], acc[i]);
        }

        // score = ||cb_k||^2 - 2*inv*(x.cb_k); ascending k + strict < keeps
        // the first minimum (numpy argmin tie-break).
        const float* kn = knorm2 + kbase;                        // uniform -> s_load
        #pragma unroll
        for (int i = 0; i < 32; ++i) {
            float s0 = fmaf(m2, acc[i], kn[i]);
            if (s0 < best) { best = s0; bestk = kbase + i; }
        }
    }

    // Epilogue: codes[b, :, h, w] = cbn[bestk, :] (divergent float4 gathers from
    // the L2-hot 128 KB table; stores coalesced across lanes per channel).
    const float4* crow4 = (const float4*)(cbn + (size_t)bestk * 64);
    float* cp = codes + ((size_t)b * 64 * 4096) + h * 64 + w;
    #pragma unroll
    for (int q = 0; q < 16; ++q) {
        float4 v = crow4[q];
        cp[(size_t)(4 * q + 0) * 4096] = v.x;
        cp[(size_t)(4 * q + 1) * 4096] = v.y;
        cp[(size_t)(4 * q + 2) * 4096] = v.z;
        cp[(size_t)(4 * q + 3) * 4096] = v.w;
    }
    idxout[(b * 64 + h) * 64 + w] = (float)bestk;
}

extern "C" void kernel_launch(void* const* d_in, const int* in_sizes, int n_in,
                              void* d_out, int out_size, void* d_ws, size_t ws_size,
                              hipStream_t stream) {
    const float* x  = (const float*)d_in[0];   // [32,64,64,64] fp32
    const float* cb = (const float*)d_in[1];   // [512,64] fp32

    float* cbn    = (float*)d_ws;              // 512*64 floats
    float* cbT    = cbn + 512 * 64;            // 64*512 floats (transposed)
    float* knorm2 = cbT + 512 * 64;            // 512 floats

    float* codes  = (float*)d_out;             // 32*64*64*64 floats
    float* idxout = codes + (size_t)32 * 64 * 64 * 64;  // 131072 floats (indices as f32)

    cb_norm_kernel<<<512, 64, 0, stream>>>(cb, cbn, cbT, knorm2);
    vq_kernel<<<512, 256, 0, stream>>>(x, cbn, cbT, knorm2, codes, idxout);
}